// Round 3
// baseline (1941.021 us; speedup 1.0000x reference)
//
#include <hip/hip_runtime.h>
#include <hip/hip_bf16.h>

#define B_DIM 2
#define T_DIM 320
#define L_DIM 207
#define D_DIM 64
#define S_DIM 21
#define J_TOT (S_DIM * L_DIM)   // 4347
#define MPAD 224                // m padded to 7*32 for K-chunks
#define NSPLIT 4
#define TSPLIT 80               // 320/4
#define NCH_A 32
#define CH_A 136                // ceil(4347/32)
#define NCH_P 128
#define CH_P 34                 // ceil(4347/128)
#define LD_ROW (L_DIM * D_DIM)  // 13248

typedef __attribute__((ext_vector_type(8))) short bf16x8;   // 8 bf16 (4 VGPRs)
typedef __attribute__((ext_vector_type(4))) float f32x4;

__device__ inline unsigned short f2bf(float f) {
    unsigned int u = __builtin_bit_cast(unsigned int, f);
    u = (u + 0x7FFFu + ((u >> 16) & 1u)) >> 16;   // RNE
    return (unsigned short)u;
}

__device__ inline int shift_p(int s) { return (s == 0) ? 287 : (21 - s); }
__device__ inline int imin(int a, int b) { return a < b ? a : b; }
__device__ inline int imax(int a, int b) { return a > b ? a : b; }

// K0: x fp32 [B,T,L,D] -> xbf bf16 [B,T,L,D] and xt bf16 [B,T,D,MPAD] (transposed, zero-padded)
__global__ void __launch_bounds__(256) k_prep(const float* __restrict__ x,
                                              unsigned short* __restrict__ xbf,
                                              unsigned short* __restrict__ xt) {
    __shared__ float tile[L_DIM * 66];
    int bt = blockIdx.x;
    const float* src = x + (size_t)bt * LD_ROW;
    int tid = threadIdx.x;
    for (int idx = tid; idx < L_DIM * D_DIM; idx += 256) {
        int l = idx >> 6, d = idx & 63;
        tile[l * 66 + d] = src[idx];
    }
    __syncthreads();
    unsigned short* dst1 = xbf + (size_t)bt * LD_ROW;
    for (int idx = tid; idx < L_DIM * D_DIM; idx += 256) {
        int l = idx >> 6, d = idx & 63;
        dst1[idx] = f2bf(tile[l * 66 + d]);
    }
    unsigned short* dst2 = xt + (size_t)bt * D_DIM * MPAD;
    if (tid < MPAD) {
        for (int d = 0; d < D_DIM; ++d) {
            float v = (tid < L_DIM) ? tile[tid * 66 + d] : 0.0f;
            dst2[d * MPAD + tid] = f2bf(v);
        }
    }
}

// ---------------- K1: logit partials -----------------------------------------
// One wave per block, 64x64 C tile (NR x NC 16-groups active), register-pipelined.
// Grid is 1-D, XCD-swizzled: low 3 bits of blockIdx.x select (b,split) so each
// XCD's L2 holds one t-window of x (~4 MB).
template <int NR, int NC>
__device__ void sim_body(const unsigned short* __restrict__ xbf, float* __restrict__ part,
                         int b, int s, int split, int l0, int m0) {
    int lane = threadIdx.x;
    int fr = lane & 15, kg = lane >> 4;
    int p = shift_p(s);
    int nt = T_DIM - p;
    int t0 = split * TSPLIT;
    int t1 = imin(t0 + TSPLIT, nt);

    int aoff[NR], boff[NC];
#pragma unroll
    for (int rg = 0; rg < NR; ++rg) {
        int r = imin(l0 + rg * 16 + fr, L_DIM - 1);   // clamp: garbage rows never stored
        aoff[rg] = r * 64 + kg * 8;
    }
#pragma unroll
    for (int cg = 0; cg < NC; ++cg) {
        int c = imin(m0 + cg * 16 + fr, L_DIM - 1);
        boff[cg] = c * 64 + kg * 8;
    }

    f32x4 acc[NR][NC];
#pragma unroll
    for (int rg = 0; rg < NR; ++rg)
#pragma unroll
        for (int cg = 0; cg < NC; ++cg) acc[rg][cg] = f32x4{0.f, 0.f, 0.f, 0.f};

    const size_t bbase = (size_t)b * T_DIM * LD_ROW;
    const unsigned short* xa0 = xbf + bbase;
    const unsigned short* xb0 = xbf + bbase + (size_t)p * LD_ROW;

    bf16x8 A0[NR], B0[NC], A1[NR], B1[NC];

    auto load = [&](bf16x8* A, bf16x8* Bv, int t, int kd) {
        const unsigned short* pa = xa0 + (size_t)t * LD_ROW + kd * 32;
        const unsigned short* pb = xb0 + (size_t)t * LD_ROW + kd * 32;
#pragma unroll
        for (int rg = 0; rg < NR; ++rg) A[rg] = *(const bf16x8*)(pa + aoff[rg]);
#pragma unroll
        for (int cg = 0; cg < NC; ++cg) Bv[cg] = *(const bf16x8*)(pb + boff[cg]);
    };
    auto domfma = [&](bf16x8* A, bf16x8* Bv) {
#pragma unroll
        for (int rg = 0; rg < NR; ++rg)
#pragma unroll
            for (int cg = 0; cg < NC; ++cg)
                acc[rg][cg] = __builtin_amdgcn_mfma_f32_16x16x32_bf16(A[rg], Bv[cg], acc[rg][cg], 0, 0, 0);
    };

    if (t1 > t0) {
        load(A0, B0, t0, 0);
        for (int t = t0; t < t1; ++t) {
            load(A1, B1, t, 1);
            domfma(A0, B0);
            if (t + 1 < t1) load(A0, B0, t + 1, 0);
            domfma(A1, B1);
        }
    }

    float* pdst = part + ((size_t)(split * B_DIM + b) * J_TOT + (size_t)s * L_DIM) * L_DIM;
#pragma unroll
    for (int rg = 0; rg < NR; ++rg)
#pragma unroll
        for (int cg = 0; cg < NC; ++cg) {
            int col = m0 + cg * 16 + fr;
            if (NC == 4 || col < L_DIM) {
#pragma unroll
                for (int r = 0; r < 4; ++r) {
                    int row = l0 + rg * 16 + kg * 4 + r;
                    if (NR == 4 || row < L_DIM) pdst[(size_t)row * L_DIM + col] = acc[rg][cg][r];
                }
            }
        }
}

__global__ void __launch_bounds__(64, 4) k_sim(const unsigned short* __restrict__ xbf,
                                               float* __restrict__ part) {
    // XCD swizzle: id&7 -> (b,split); each XCD sees one t-window of x.
    int id = blockIdx.x;
    int bsplit = id & 7;
    int b = bsplit >> 2, split = bsplit & 3;
    int rest = id >> 3;          // 0..335
    int s = rest / 16;           // 0..20
    int tile = rest & 15;
    int lt = tile >> 2, mt = tile & 3;
    int l0 = lt * 64, m0 = mt * 64;
    if (lt < 3) {
        if (mt < 3) sim_body<4, 4>(xbf, part, b, s, split, l0, m0);
        else        sim_body<4, 1>(xbf, part, b, s, split, l0, m0);
    } else {
        if (mt < 3) sim_body<1, 4>(xbf, part, b, s, split, l0, m0);
        else        sim_body<1, 1>(xbf, part, b, s, split, l0, m0);
    }
}

// K2: partial sum of exp over j-chunks. grid (NCH_A, B), block 256 (thread = m).
__global__ void __launch_bounds__(256) k_sumexp(const float* __restrict__ part,
                                                const float* __restrict__ w,
                                                float* __restrict__ psum) {
    int c = blockIdx.x, b = blockIdx.y;
    int m = threadIdx.x;
    if (m >= L_DIM) return;
    float scale = w[0] / (float)T_DIM;
    int j0 = c * CH_A, j1 = imin(j0 + CH_A, J_TOT);
    float acc = 0.0f;
    for (int j = j0; j < j1; ++j) {
        float v = 0.0f;
#pragma unroll
        for (int r = 0; r < NSPLIT; ++r)
            v += part[((size_t)(r * B_DIM + b) * J_TOT + j) * L_DIM + m];
        acc += __expf(v * scale);
    }
    psum[(b * NCH_A + c) * L_DIM + m] = acc;
}

// K3: pack probs to bf16 [B][J_TOT][MPAD], zero-padded in m. grid (NCH_P, B), block 256.
__global__ void __launch_bounds__(256) k_pack(const float* __restrict__ part,
                                              const float* __restrict__ w,
                                              const float* __restrict__ psum,
                                              unsigned short* __restrict__ pp) {
    __shared__ float sinv[L_DIM];
    int c = blockIdx.x, b = blockIdx.y;
    int tid = threadIdx.x;
    if (tid < L_DIM) {
        float g = 0.0f;
        for (int q = 0; q < NCH_A; ++q) g += psum[(b * NCH_A + q) * L_DIM + tid];
        sinv[tid] = 1.0f / g;
    }
    __syncthreads();
    if (tid >= MPAD) return;
    float scale = w[0] / (float)T_DIM;
    float inv = (tid < L_DIM) ? sinv[tid] : 0.0f;
    int j0 = c * CH_P, j1 = imin(j0 + CH_P, J_TOT);
    for (int j = j0; j < j1; ++j) {
        float pr = 0.0f;
        if (tid < L_DIM) {
            float v = 0.0f;
#pragma unroll
            for (int r = 0; r < NSPLIT; ++r)
                v += part[((size_t)(r * B_DIM + b) * J_TOT + j) * L_DIM + tid];
            pr = __expf(v * scale) * inv;
        }
        pp[((size_t)b * J_TOT + j) * MPAD + tid] = f2bf(pr);
    }
}

// ---------------- K4: out = P @ x_shift --------------------------------------
// One wave per block: 64(i) x 64(d) C tile, NR 16-row groups active.
// Grid 1-D XCD-swizzled: low 3 bits -> (b, t-quarter).
template <int NR>
__device__ void out_body(const unsigned short* __restrict__ pp,
                         const unsigned short* __restrict__ xt,
                         float* __restrict__ out, int b, int t, int i0) {
    int lane = threadIdx.x;
    int fr = lane & 15, kg = lane >> 4;

    int aoff[NR];
#pragma unroll
    for (int rg = 0; rg < NR; ++rg) {
        int i = imin(i0 + rg * 16 + fr, L_DIM - 1);
        aoff[rg] = i * (S_DIM * MPAD) + kg * 8;
    }
    int boff[4];
#pragma unroll
    for (int cg = 0; cg < 4; ++cg) boff[cg] = (cg * 16 + fr) * MPAD + kg * 8;

    const unsigned short* pbase = pp + (size_t)b * J_TOT * MPAD;
    const unsigned short* xtb = xt + (size_t)b * T_DIM * D_DIM * MPAD;

    f32x4 acc[NR][4];
#pragma unroll
    for (int rg = 0; rg < NR; ++rg)
#pragma unroll
        for (int cg = 0; cg < 4; ++cg) acc[rg][cg] = f32x4{0.f, 0.f, 0.f, 0.f};

    bf16x8 A0[NR], B0[4], A1[NR], B1[4];

    auto load = [&](bf16x8* A, bf16x8* Bv, int s, int mc) {
        const unsigned short* pa = pbase + s * MPAD + mc * 32;
        const unsigned short* pb = xtb + (size_t)(t + shift_p(s)) * (D_DIM * MPAD) + mc * 32;
#pragma unroll
        for (int rg = 0; rg < NR; ++rg) A[rg] = *(const bf16x8*)(pa + aoff[rg]);
#pragma unroll
        for (int cg = 0; cg < 4; ++cg) Bv[cg] = *(const bf16x8*)(pb + boff[cg]);
    };
    auto domfma = [&](bf16x8* A, bf16x8* Bv) {
#pragma unroll
        for (int rg = 0; rg < NR; ++rg)
#pragma unroll
            for (int cg = 0; cg < 4; ++cg)
                acc[rg][cg] = __builtin_amdgcn_mfma_f32_16x16x32_bf16(A[rg], Bv[cg], acc[rg][cg], 0, 0, 0);
    };

    int smin = imax(1, t - 298);
    bool has0 = (t < T_DIM - 287);   // t < 33
    int sA = has0 ? 0 : smin;
    if (sA <= 20) {
        load(A0, B0, sA, 0);
        int s1 = sA, mc1 = 0;
        while (true) {
            int s2 = s1, mc2 = mc1 + 1;
            if (mc2 == 7) { mc2 = 0; s2 = (s1 == 0) ? smin : s1 + 1; }
            bool have2 = (s2 <= 20);
            if (have2) load(A1, B1, s2, mc2);
            domfma(A0, B0);
            if (!have2) break;
            int s3 = s2, mc3 = mc2 + 1;
            if (mc3 == 7) { mc3 = 0; s3 = (s2 == 0) ? smin : s2 + 1; }
            bool have3 = (s3 <= 20);
            if (have3) load(A0, B0, s3, mc3);
            domfma(A1, B1);
            if (!have3) break;
            s1 = s3; mc1 = mc3;
        }
    }

    float* obase = out + (size_t)(b * T_DIM + t) * LD_ROW;
#pragma unroll
    for (int rg = 0; rg < NR; ++rg)
#pragma unroll
        for (int cg = 0; cg < 4; ++cg) {
            int d = cg * 16 + fr;
#pragma unroll
            for (int r = 0; r < 4; ++r) {
                int i = i0 + rg * 16 + kg * 4 + r;
                if (NR == 4 || i < L_DIM) obase[(size_t)i * D_DIM + d] = acc[rg][cg][r];
            }
        }
}

__global__ void __launch_bounds__(64, 4) k_out(const unsigned short* __restrict__ pp,
                                               const unsigned short* __restrict__ xt,
                                               float* __restrict__ out) {
    // XCD swizzle: id&7 -> (b, t-quarter); each XCD reads one xt t-window.
    int id = blockIdx.x;
    int low = id & 7;
    int b = low >> 2, tq = low & 3;
    int rest = id >> 3;          // 0..319
    int tt = rest >> 2;          // 0..79
    int it = rest & 3;
    int t = tq * TSPLIT + tt;
    int i0 = it * 64;
    if (it < 3) out_body<4>(pp, xt, out, b, t, i0);
    else        out_body<1>(pp, xt, out, b, t, i0);
}

extern "C" void kernel_launch(void* const* d_in, const int* in_sizes, int n_in,
                              void* d_out, int out_size, void* d_ws, size_t ws_size,
                              hipStream_t stream) {
    const float* x = (const float*)d_in[0];
    const float* w = (const float*)d_in[1];
    float* out = (float*)d_out;

    char* ws = (char*)d_ws;
    size_t off = 0;
    auto carve = [&](size_t bytes) {
        void* p = ws + off;
        off += (bytes + 255) & ~(size_t)255;
        return p;
    };
    unsigned short* xbf = (unsigned short*)carve((size_t)B_DIM * T_DIM * LD_ROW * 2);          // 17.0 MB
    unsigned short* xt  = (unsigned short*)carve((size_t)B_DIM * T_DIM * D_DIM * MPAD * 2);    // 18.4 MB
    float* part         = (float*)carve((size_t)NSPLIT * B_DIM * J_TOT * L_DIM * 4);           // 28.8 MB
    float* psum         = (float*)carve((size_t)B_DIM * NCH_A * L_DIM * 4);                    // 53 KB
    unsigned short* pp  = (unsigned short*)carve((size_t)B_DIM * J_TOT * MPAD * 2);            // 3.9 MB

    k_prep<<<B_DIM * T_DIM, 256, 0, stream>>>(x, xbf, xt);
    k_sim<<<42 * 16 * NSPLIT, 64, 0, stream>>>(xbf, part);
    k_sumexp<<<dim3(NCH_A, B_DIM), 256, 0, stream>>>(part, w, psum);
    k_pack<<<dim3(NCH_P, B_DIM), 256, 0, stream>>>(part, w, psum, pp);
    k_out<<<B_DIM * T_DIM * 4, 64, 0, stream>>>(pp, xt, out);
}

// Round 4
// 843.699 us; speedup vs baseline: 2.3006x; 2.3006x over previous
//
#include <hip/hip_runtime.h>
#include <hip/hip_bf16.h>

#define B_DIM 2
#define T_DIM 320
#define L_DIM 207
#define D_DIM 64
#define S_DIM 21
#define J_TOT (S_DIM * L_DIM)   // 4347
#define MPAD 224                // m padded to 7*32 for K-chunks
#define NSPLIT 4
#define TSPLIT 80               // 320/4
#define NCH_A 32
#define CH_A 136                // ceil(4347/32)
#define NCH_P 128
#define CH_P 34                 // ceil(4347/128)
#define LD_ROW (L_DIM * D_DIM)  // 13248

typedef __attribute__((ext_vector_type(8))) short bf16x8;   // 8 bf16 (4 VGPRs)
typedef __attribute__((ext_vector_type(4))) float f32x4;

__device__ inline unsigned short f2bf(float f) {
    unsigned int u = __builtin_bit_cast(unsigned int, f);
    u = (u + 0x7FFFu + ((u >> 16) & 1u)) >> 16;   // RNE
    return (unsigned short)u;
}

__device__ inline int shift_p(int s) { return (s == 0) ? 287 : (21 - s); }
__device__ inline int imin(int a, int b) { return a < b ? a : b; }
__device__ inline int imax(int a, int b) { return a > b ? a : b; }

// K0: x fp32 [B,T,L,D] -> xbf bf16 [B,T,L,D] and xt bf16 [B,T,D,MPAD] (transposed, zero-padded)
__global__ void __launch_bounds__(256) k_prep(const float* __restrict__ x,
                                              unsigned short* __restrict__ xbf,
                                              unsigned short* __restrict__ xt) {
    __shared__ float tile[L_DIM * 66];
    int bt = blockIdx.x;
    const float* src = x + (size_t)bt * LD_ROW;
    int tid = threadIdx.x;
    for (int idx = tid; idx < L_DIM * D_DIM; idx += 256) {
        int l = idx >> 6, d = idx & 63;
        tile[l * 66 + d] = src[idx];
    }
    __syncthreads();
    unsigned short* dst1 = xbf + (size_t)bt * LD_ROW;
    for (int idx = tid; idx < L_DIM * D_DIM; idx += 256) {
        int l = idx >> 6, d = idx & 63;
        dst1[idx] = f2bf(tile[l * 66 + d]);
    }
    unsigned short* dst2 = xt + (size_t)bt * D_DIM * MPAD;
    if (tid < MPAD) {
        for (int d = 0; d < D_DIM; ++d) {
            float v = (tid < L_DIM) ? tile[tid * 66 + d] : 0.0f;
            dst2[d * MPAD + tid] = f2bf(v);
        }
    }
}

// ---------------- K1: logit partials -----------------------------------------
// One wave per block, 64x64 C tile (NR x NC 16-groups active), register-pipelined.
// Grid is 1-D, XCD-swizzled: low 3 bits of blockIdx.x select (b,split) so each
// XCD's L2 holds one t-window of x (~4 MB).
template <int NR, int NC>
__device__ void sim_body(const unsigned short* __restrict__ xbf, float* __restrict__ part,
                         int b, int s, int split, int l0, int m0) {
    int lane = threadIdx.x;
    int fr = lane & 15, kg = lane >> 4;
    int p = shift_p(s);
    int nt = T_DIM - p;
    int t0 = split * TSPLIT;
    int t1 = imin(t0 + TSPLIT, nt);

    int aoff[NR], boff[NC];
#pragma unroll
    for (int rg = 0; rg < NR; ++rg) {
        int r = imin(l0 + rg * 16 + fr, L_DIM - 1);   // clamp: garbage rows never stored
        aoff[rg] = r * 64 + kg * 8;
    }
#pragma unroll
    for (int cg = 0; cg < NC; ++cg) {
        int c = imin(m0 + cg * 16 + fr, L_DIM - 1);
        boff[cg] = c * 64 + kg * 8;
    }

    f32x4 acc[NR][NC];
#pragma unroll
    for (int rg = 0; rg < NR; ++rg)
#pragma unroll
        for (int cg = 0; cg < NC; ++cg) acc[rg][cg] = f32x4{0.f, 0.f, 0.f, 0.f};

    const size_t bbase = (size_t)b * T_DIM * LD_ROW;
    const unsigned short* xa0 = xbf + bbase;
    const unsigned short* xb0 = xbf + bbase + (size_t)p * LD_ROW;

    bf16x8 A0[NR], B0[NC], A1[NR], B1[NC];

    auto load = [&](bf16x8* A, bf16x8* Bv, int t, int kd) {
        const unsigned short* pa = xa0 + (size_t)t * LD_ROW + kd * 32;
        const unsigned short* pb = xb0 + (size_t)t * LD_ROW + kd * 32;
#pragma unroll
        for (int rg = 0; rg < NR; ++rg) A[rg] = *(const bf16x8*)(pa + aoff[rg]);
#pragma unroll
        for (int cg = 0; cg < NC; ++cg) Bv[cg] = *(const bf16x8*)(pb + boff[cg]);
    };
    auto domfma = [&](bf16x8* A, bf16x8* Bv) {
#pragma unroll
        for (int rg = 0; rg < NR; ++rg)
#pragma unroll
            for (int cg = 0; cg < NC; ++cg)
                acc[rg][cg] = __builtin_amdgcn_mfma_f32_16x16x32_bf16(A[rg], Bv[cg], acc[rg][cg], 0, 0, 0);
    };

    if (t1 > t0) {
        load(A0, B0, t0, 0);
        for (int t = t0; t < t1; ++t) {
            load(A1, B1, t, 1);
            domfma(A0, B0);
            if (t + 1 < t1) load(A0, B0, t + 1, 0);
            domfma(A1, B1);
        }
    }

    float* pdst = part + ((size_t)(split * B_DIM + b) * J_TOT + (size_t)s * L_DIM) * L_DIM;
#pragma unroll
    for (int rg = 0; rg < NR; ++rg)
#pragma unroll
        for (int cg = 0; cg < NC; ++cg) {
            int col = m0 + cg * 16 + fr;
            if (NC == 4 || col < L_DIM) {
#pragma unroll
                for (int r = 0; r < 4; ++r) {
                    int row = l0 + rg * 16 + kg * 4 + r;
                    if (NR == 4 || row < L_DIM) pdst[(size_t)row * L_DIM + col] = acc[rg][cg][r];
                }
            }
        }
}

__global__ void __launch_bounds__(64) k_sim(const unsigned short* __restrict__ xbf,
                                            float* __restrict__ part) {
    // XCD swizzle: id&7 -> (b,split); each XCD sees one t-window of x.
    int id = blockIdx.x;
    int bsplit = id & 7;
    int b = bsplit >> 2, split = bsplit & 3;
    int rest = id >> 3;          // 0..335
    int s = rest / 16;           // 0..20
    int tile = rest & 15;
    int lt = tile >> 2, mt = tile & 3;
    int l0 = lt * 64, m0 = mt * 64;
    if (lt < 3) {
        if (mt < 3) sim_body<4, 4>(xbf, part, b, s, split, l0, m0);
        else        sim_body<4, 1>(xbf, part, b, s, split, l0, m0);
    } else {
        if (mt < 3) sim_body<1, 4>(xbf, part, b, s, split, l0, m0);
        else        sim_body<1, 1>(xbf, part, b, s, split, l0, m0);
    }
}

// K2: partial sum of exp over j-chunks. grid (NCH_A, B), block 256 (thread = m).
__global__ void __launch_bounds__(256) k_sumexp(const float* __restrict__ part,
                                                const float* __restrict__ w,
                                                float* __restrict__ psum) {
    int c = blockIdx.x, b = blockIdx.y;
    int m = threadIdx.x;
    if (m >= L_DIM) return;
    float scale = w[0] / (float)T_DIM;
    int j0 = c * CH_A, j1 = imin(j0 + CH_A, J_TOT);
    float acc = 0.0f;
    for (int j = j0; j < j1; ++j) {
        float v = 0.0f;
#pragma unroll
        for (int r = 0; r < NSPLIT; ++r)
            v += part[((size_t)(r * B_DIM + b) * J_TOT + j) * L_DIM + m];
        acc += __expf(v * scale);
    }
    psum[(b * NCH_A + c) * L_DIM + m] = acc;
}

// K3: pack probs to bf16 [B][J_TOT][MPAD], zero-padded in m. grid (NCH_P, B), block 256.
__global__ void __launch_bounds__(256) k_pack(const float* __restrict__ part,
                                              const float* __restrict__ w,
                                              const float* __restrict__ psum,
                                              unsigned short* __restrict__ pp) {
    __shared__ float sinv[L_DIM];
    int c = blockIdx.x, b = blockIdx.y;
    int tid = threadIdx.x;
    if (tid < L_DIM) {
        float g = 0.0f;
        for (int q = 0; q < NCH_A; ++q) g += psum[(b * NCH_A + q) * L_DIM + tid];
        sinv[tid] = 1.0f / g;
    }
    __syncthreads();
    if (tid >= MPAD) return;
    float scale = w[0] / (float)T_DIM;
    float inv = (tid < L_DIM) ? sinv[tid] : 0.0f;
    int j0 = c * CH_P, j1 = imin(j0 + CH_P, J_TOT);
    for (int j = j0; j < j1; ++j) {
        float pr = 0.0f;
        if (tid < L_DIM) {
            float v = 0.0f;
#pragma unroll
            for (int r = 0; r < NSPLIT; ++r)
                v += part[((size_t)(r * B_DIM + b) * J_TOT + j) * L_DIM + tid];
            pr = __expf(v * scale) * inv;
        }
        pp[((size_t)b * J_TOT + j) * MPAD + tid] = f2bf(pr);
    }
}

// ---------------- K4: out = P @ x_shift --------------------------------------
// One wave per block: 64(i) x 64(d) C tile, NR 16-row groups active.
// Grid 1-D XCD-swizzled: low 3 bits -> (b, t-quarter).
template <int NR>
__device__ void out_body(const unsigned short* __restrict__ pp,
                         const unsigned short* __restrict__ xt,
                         float* __restrict__ out, int b, int t, int i0) {
    int lane = threadIdx.x;
    int fr = lane & 15, kg = lane >> 4;

    int aoff[NR];
#pragma unroll
    for (int rg = 0; rg < NR; ++rg) {
        int i = imin(i0 + rg * 16 + fr, L_DIM - 1);
        aoff[rg] = i * (S_DIM * MPAD) + kg * 8;
    }
    int boff[4];
#pragma unroll
    for (int cg = 0; cg < 4; ++cg) boff[cg] = (cg * 16 + fr) * MPAD + kg * 8;

    const unsigned short* pbase = pp + (size_t)b * J_TOT * MPAD;
    const unsigned short* xtb = xt + (size_t)b * T_DIM * D_DIM * MPAD;

    f32x4 acc[NR][4];
#pragma unroll
    for (int rg = 0; rg < NR; ++rg)
#pragma unroll
        for (int cg = 0; cg < 4; ++cg) acc[rg][cg] = f32x4{0.f, 0.f, 0.f, 0.f};

    bf16x8 A0[NR], B0[4], A1[NR], B1[4];

    auto load = [&](bf16x8* A, bf16x8* Bv, int s, int mc) {
        const unsigned short* pa = pbase + s * MPAD + mc * 32;
        const unsigned short* pb = xtb + (size_t)(t + shift_p(s)) * (D_DIM * MPAD) + mc * 32;
#pragma unroll
        for (int rg = 0; rg < NR; ++rg) A[rg] = *(const bf16x8*)(pa + aoff[rg]);
#pragma unroll
        for (int cg = 0; cg < 4; ++cg) Bv[cg] = *(const bf16x8*)(pb + boff[cg]);
    };
    auto domfma = [&](bf16x8* A, bf16x8* Bv) {
#pragma unroll
        for (int rg = 0; rg < NR; ++rg)
#pragma unroll
            for (int cg = 0; cg < 4; ++cg)
                acc[rg][cg] = __builtin_amdgcn_mfma_f32_16x16x32_bf16(A[rg], Bv[cg], acc[rg][cg], 0, 0, 0);
    };

    int smin = imax(1, t - 298);
    bool has0 = (t < T_DIM - 287);   // t < 33
    int sA = has0 ? 0 : smin;
    if (sA <= 20) {
        load(A0, B0, sA, 0);
        int s1 = sA, mc1 = 0;
        while (true) {
            int s2 = s1, mc2 = mc1 + 1;
            if (mc2 == 7) { mc2 = 0; s2 = (s1 == 0) ? smin : s1 + 1; }
            bool have2 = (s2 <= 20);
            if (have2) load(A1, B1, s2, mc2);
            domfma(A0, B0);
            if (!have2) break;
            int s3 = s2, mc3 = mc2 + 1;
            if (mc3 == 7) { mc3 = 0; s3 = (s2 == 0) ? smin : s2 + 1; }
            bool have3 = (s3 <= 20);
            if (have3) load(A0, B0, s3, mc3);
            domfma(A1, B1);
            if (!have3) break;
            s1 = s3; mc1 = mc3;
        }
    }

    float* obase = out + (size_t)(b * T_DIM + t) * LD_ROW;
#pragma unroll
    for (int rg = 0; rg < NR; ++rg)
#pragma unroll
        for (int cg = 0; cg < 4; ++cg) {
            int d = cg * 16 + fr;
#pragma unroll
            for (int r = 0; r < 4; ++r) {
                int i = i0 + rg * 16 + kg * 4 + r;
                if (NR == 4 || i < L_DIM) obase[(size_t)i * D_DIM + d] = acc[rg][cg][r];
            }
        }
}

__global__ void __launch_bounds__(64) k_out(const unsigned short* __restrict__ pp,
                                            const unsigned short* __restrict__ xt,
                                            float* __restrict__ out) {
    // XCD swizzle: id&7 -> (b, t-quarter); each XCD reads one xt t-window.
    int id = blockIdx.x;
    int low = id & 7;
    int b = low >> 2, tq = low & 3;
    int rest = id >> 3;          // 0..319
    int tt = rest >> 2;          // 0..79
    int it = rest & 3;
    int t = tq * TSPLIT + tt;
    int i0 = it * 64;
    if (it < 3) out_body<4>(pp, xt, out, b, t, i0);
    else        out_body<1>(pp, xt, out, b, t, i0);
}

extern "C" void kernel_launch(void* const* d_in, const int* in_sizes, int n_in,
                              void* d_out, int out_size, void* d_ws, size_t ws_size,
                              hipStream_t stream) {
    const float* x = (const float*)d_in[0];
    const float* w = (const float*)d_in[1];
    float* out = (float*)d_out;

    char* ws = (char*)d_ws;
    size_t off = 0;
    auto carve = [&](size_t bytes) {
        void* p = ws + off;
        off += (bytes + 255) & ~(size_t)255;
        return p;
    };
    unsigned short* xbf = (unsigned short*)carve((size_t)B_DIM * T_DIM * LD_ROW * 2);          // 17.0 MB
    unsigned short* xt  = (unsigned short*)carve((size_t)B_DIM * T_DIM * D_DIM * MPAD * 2);    // 18.4 MB
    float* part         = (float*)carve((size_t)NSPLIT * B_DIM * J_TOT * L_DIM * 4);           // 28.8 MB
    float* psum         = (float*)carve((size_t)B_DIM * NCH_A * L_DIM * 4);                    // 53 KB
    unsigned short* pp  = (unsigned short*)carve((size_t)B_DIM * J_TOT * MPAD * 2);            // 3.9 MB

    k_prep<<<B_DIM * T_DIM, 256, 0, stream>>>(x, xbf, xt);
    k_sim<<<42 * 16 * NSPLIT, 64, 0, stream>>>(xbf, part);
    k_sumexp<<<dim3(NCH_A, B_DIM), 256, 0, stream>>>(part, w, psum);
    k_pack<<<dim3(NCH_P, B_DIM), 256, 0, stream>>>(part, w, psum, pp);
    k_out<<<B_DIM * T_DIM * 4, 64, 0, stream>>>(pp, xt, out);
}

// Round 5
// 577.916 us; speedup vs baseline: 3.3587x; 1.4599x over previous
//
#include <hip/hip_runtime.h>
#include <hip/hip_bf16.h>

#define B_DIM 2
#define T_DIM 320
#define L_DIM 207
#define D_DIM 64
#define S_DIM 21
#define J_TOT (S_DIM * L_DIM)   // 4347
#define MPAD 224                // m padded to 7*32 for K-chunks
#define NSPLIT 4
#define TSPLIT 80               // 320/4
#define NCH_A 32
#define CH_A 136                // ceil(4347/32)
#define NCH_P 128
#define CH_P 34                 // ceil(4347/128)
#define LD_ROW (L_DIM * D_DIM)  // 13248
#define LROW 72                 // LDS row stride in elems (64 + 8 pad -> conflict-free frag reads)

typedef __attribute__((ext_vector_type(8))) short bf16x8;   // 8 bf16 (4 VGPRs)
typedef __attribute__((ext_vector_type(4))) float f32x4;

__device__ inline unsigned short f2bf(float f) {
    unsigned int u = __builtin_bit_cast(unsigned int, f);
    u = (u + 0x7FFFu + ((u >> 16) & 1u)) >> 16;   // RNE
    return (unsigned short)u;
}

__device__ inline int shift_p(int s) { return (s == 0) ? 287 : (21 - s); }
__device__ inline int imin(int a, int b) { return a < b ? a : b; }
__device__ inline int imax(int a, int b) { return a > b ? a : b; }

// K0: x fp32 [B,T,L,D] -> xbf bf16 [B,T,L,D] and xt bf16 [B,T,D,MPAD] (transposed, zero-padded)
__global__ void __launch_bounds__(256) k_prep(const float* __restrict__ x,
                                              unsigned short* __restrict__ xbf,
                                              unsigned short* __restrict__ xt) {
    __shared__ float tile[L_DIM * 66];
    int bt = blockIdx.x;
    const float* src = x + (size_t)bt * LD_ROW;
    int tid = threadIdx.x;
    for (int idx = tid; idx < L_DIM * D_DIM; idx += 256) {
        int l = idx >> 6, d = idx & 63;
        tile[l * 66 + d] = src[idx];
    }
    __syncthreads();
    unsigned short* dst1 = xbf + (size_t)bt * LD_ROW;
    for (int idx = tid; idx < L_DIM * D_DIM; idx += 256) {
        int l = idx >> 6, d = idx & 63;
        dst1[idx] = f2bf(tile[l * 66 + d]);
    }
    unsigned short* dst2 = xt + (size_t)bt * D_DIM * MPAD;
    if (tid < MPAD) {
        for (int d = 0; d < D_DIM; ++d) {
            float v = (tid < L_DIM) ? tile[tid * 66 + d] : 0.0f;
            dst2[d * MPAD + tid] = f2bf(v);
        }
    }
}

// ---------------- K1: logit partials (LDS-staged, 4 waves, 128x128 C) --------
// Grid flat 672 = 8 * 84; low 3 bits = (b,split) XCD swizzle. rest: s(21) x tile(4: 2x2 of 128).
// Per t: stage A-slab [128 l x 64 d] + B-slab [128 m x 64 d] (contiguous in global)
// into padded LDS; each wave computes a 64x64 quadrant from LDS.
__global__ void __launch_bounds__(256) k_sim(const unsigned short* __restrict__ xbf,
                                             float* __restrict__ part) {
    __shared__ __align__(16) unsigned short As[128 * LROW];
    __shared__ __align__(16) unsigned short Bs[128 * LROW];

    int id = blockIdx.x;
    int bsplit = id & 7;
    int b = bsplit >> 2, split = bsplit & 3;
    int rest = id >> 3;          // 0..83
    int s = rest >> 2;           // 0..20
    int tile = rest & 3;
    int l0 = (tile >> 1) * 128, m0 = (tile & 1) * 128;

    int p = shift_p(s);
    int nt = T_DIM - p;
    int t0 = split * TSPLIT;
    int t1 = imin(t0 + TSPLIT, nt);

    int tid = threadIdx.x;
    int wave = tid >> 6, lane = tid & 63;
    int wl = wave >> 1, wm = wave & 1;
    int fr = lane & 15, kg = lane >> 4;

    // staging map: thread -> (row = tid/2, 64B half = tid&1), 4 x 16B chunks
    int sr = tid >> 1, sh = tid & 1;
    int goff = sr * 64 + sh * 32;        // elems within slab (row stride 64)
    int loff = sr * LROW + sh * 32;      // elems within LDS (row stride 72)

    // fragment LDS offsets (elems)
    int afo[4], bfo[4];
#pragma unroll
    for (int rg = 0; rg < 4; ++rg) afo[rg] = (wl * 64 + rg * 16 + fr) * LROW + kg * 8;
#pragma unroll
    for (int cg = 0; cg < 4; ++cg) bfo[cg] = (wm * 64 + cg * 16 + fr) * LROW + kg * 8;

    f32x4 acc[4][4];
#pragma unroll
    for (int i = 0; i < 4; ++i)
#pragma unroll
        for (int j = 0; j < 4; ++j) acc[i][j] = f32x4{0.f, 0.f, 0.f, 0.f};

    const size_t bbase = (size_t)b * T_DIM * LD_ROW;
    const unsigned short* ga = xbf + bbase + (size_t)l0 * 64;                      // A slab base (t=0)
    const unsigned short* gb = xbf + bbase + (size_t)p * LD_ROW + (size_t)m0 * 64; // B slab base (t=0)

    for (int t = t0; t < t1; ++t) {
        const unsigned short* pa = ga + (size_t)t * LD_ROW + goff;
        const unsigned short* pb = gb + (size_t)t * LD_ROW + goff;
        bf16x8 va[4], vb[4];
#pragma unroll
        for (int c = 0; c < 4; ++c) {
            va[c] = *(const bf16x8*)(pa + c * 8);
            vb[c] = *(const bf16x8*)(pb + c * 8);
        }
        __syncthreads();   // previous iteration's fragment reads complete
#pragma unroll
        for (int c = 0; c < 4; ++c) {
            *(bf16x8*)(As + loff + c * 8) = va[c];
            *(bf16x8*)(Bs + loff + c * 8) = vb[c];
        }
        __syncthreads();   // slabs visible
#pragma unroll
        for (int kd = 0; kd < 2; ++kd) {
            bf16x8 af[4], bv[4];
#pragma unroll
            for (int rg = 0; rg < 4; ++rg) af[rg] = *(const bf16x8*)(As + afo[rg] + kd * 32);
#pragma unroll
            for (int cg = 0; cg < 4; ++cg) bv[cg] = *(const bf16x8*)(Bs + bfo[cg] + kd * 32);
#pragma unroll
            for (int rg = 0; rg < 4; ++rg)
#pragma unroll
                for (int cg = 0; cg < 4; ++cg)
                    acc[rg][cg] = __builtin_amdgcn_mfma_f32_16x16x32_bf16(af[rg], bv[cg], acc[rg][cg], 0, 0, 0);
        }
    }

    float* pdst = part + ((size_t)(split * B_DIM + b) * J_TOT + (size_t)s * L_DIM) * L_DIM;
#pragma unroll
    for (int rg = 0; rg < 4; ++rg)
#pragma unroll
        for (int cg = 0; cg < 4; ++cg) {
            int col = m0 + wm * 64 + cg * 16 + fr;
            if (col < L_DIM) {
#pragma unroll
                for (int r = 0; r < 4; ++r) {
                    int row = l0 + wl * 64 + rg * 16 + kg * 4 + r;
                    if (row < L_DIM) pdst[(size_t)row * L_DIM + col] = acc[rg][cg][r];
                }
            }
        }
}

// K2: partial sum of exp over j-chunks. grid (NCH_A, B), block 256 (thread = m).
__global__ void __launch_bounds__(256) k_sumexp(const float* __restrict__ part,
                                                const float* __restrict__ w,
                                                float* __restrict__ psum) {
    int c = blockIdx.x, b = blockIdx.y;
    int m = threadIdx.x;
    if (m >= L_DIM) return;
    float scale = w[0] / (float)T_DIM;
    int j0 = c * CH_A, j1 = imin(j0 + CH_A, J_TOT);
    float acc = 0.0f;
    for (int j = j0; j < j1; ++j) {
        float v = 0.0f;
#pragma unroll
        for (int r = 0; r < NSPLIT; ++r)
            v += part[((size_t)(r * B_DIM + b) * J_TOT + j) * L_DIM + m];
        acc += __expf(v * scale);
    }
    psum[(b * NCH_A + c) * L_DIM + m] = acc;
}

// K3: pack probs to bf16 [B][J_TOT][MPAD], zero-padded in m. grid (NCH_P, B), block 256.
__global__ void __launch_bounds__(256) k_pack(const float* __restrict__ part,
                                              const float* __restrict__ w,
                                              const float* __restrict__ psum,
                                              unsigned short* __restrict__ pp) {
    __shared__ float sinv[L_DIM];
    int c = blockIdx.x, b = blockIdx.y;
    int tid = threadIdx.x;
    if (tid < L_DIM) {
        float g = 0.0f;
        for (int q = 0; q < NCH_A; ++q) g += psum[(b * NCH_A + q) * L_DIM + tid];
        sinv[tid] = 1.0f / g;
    }
    __syncthreads();
    if (tid >= MPAD) return;
    float scale = w[0] / (float)T_DIM;
    float inv = (tid < L_DIM) ? sinv[tid] : 0.0f;
    int j0 = c * CH_P, j1 = imin(j0 + CH_P, J_TOT);
    for (int j = j0; j < j1; ++j) {
        float pr = 0.0f;
        if (tid < L_DIM) {
            float v = 0.0f;
#pragma unroll
            for (int r = 0; r < NSPLIT; ++r)
                v += part[((size_t)(r * B_DIM + b) * J_TOT + j) * L_DIM + tid];
            pr = __expf(v * scale) * inv;
        }
        pp[((size_t)b * J_TOT + j) * MPAD + tid] = f2bf(pr);
    }
}

// ---------------- K4: out = P @ x_shift --------------------------------------
// One wave per block: 64(i) x 64(d) C tile, NR 16-row groups active.
// Grid 1-D XCD-swizzled: low 3 bits -> (b, t-quarter).
template <int NR>
__device__ void out_body(const unsigned short* __restrict__ pp,
                         const unsigned short* __restrict__ xt,
                         float* __restrict__ out, int b, int t, int i0) {
    int lane = threadIdx.x;
    int fr = lane & 15, kg = lane >> 4;

    int aoff[NR];
#pragma unroll
    for (int rg = 0; rg < NR; ++rg) {
        int i = imin(i0 + rg * 16 + fr, L_DIM - 1);
        aoff[rg] = i * (S_DIM * MPAD) + kg * 8;
    }
    int boff[4];
#pragma unroll
    for (int cg = 0; cg < 4; ++cg) boff[cg] = (cg * 16 + fr) * MPAD + kg * 8;

    const unsigned short* pbase = pp + (size_t)b * J_TOT * MPAD;
    const unsigned short* xtb = xt + (size_t)b * T_DIM * D_DIM * MPAD;

    f32x4 acc[NR][4];
#pragma unroll
    for (int rg = 0; rg < NR; ++rg)
#pragma unroll
        for (int cg = 0; cg < 4; ++cg) acc[rg][cg] = f32x4{0.f, 0.f, 0.f, 0.f};

    bf16x8 A0[NR], B0[4], A1[NR], B1[4];

    auto load = [&](bf16x8* A, bf16x8* Bv, int s, int mc) {
        const unsigned short* pa = pbase + s * MPAD + mc * 32;
        const unsigned short* pb = xtb + (size_t)(t + shift_p(s)) * (D_DIM * MPAD) + mc * 32;
#pragma unroll
        for (int rg = 0; rg < NR; ++rg) A[rg] = *(const bf16x8*)(pa + aoff[rg]);
#pragma unroll
        for (int cg = 0; cg < 4; ++cg) Bv[cg] = *(const bf16x8*)(pb + boff[cg]);
    };
    auto domfma = [&](bf16x8* A, bf16x8* Bv) {
#pragma unroll
        for (int rg = 0; rg < NR; ++rg)
#pragma unroll
            for (int cg = 0; cg < 4; ++cg)
                acc[rg][cg] = __builtin_amdgcn_mfma_f32_16x16x32_bf16(A[rg], Bv[cg], acc[rg][cg], 0, 0, 0);
    };

    int smin = imax(1, t - 298);
    bool has0 = (t < T_DIM - 287);   // t < 33
    int sA = has0 ? 0 : smin;
    if (sA <= 20) {
        load(A0, B0, sA, 0);
        int s1 = sA, mc1 = 0;
        while (true) {
            int s2 = s1, mc2 = mc1 + 1;
            if (mc2 == 7) { mc2 = 0; s2 = (s1 == 0) ? smin : s1 + 1; }
            bool have2 = (s2 <= 20);
            if (have2) load(A1, B1, s2, mc2);
            domfma(A0, B0);
            if (!have2) break;
            int s3 = s2, mc3 = mc2 + 1;
            if (mc3 == 7) { mc3 = 0; s3 = (s2 == 0) ? smin : s2 + 1; }
            bool have3 = (s3 <= 20);
            if (have3) load(A0, B0, s3, mc3);
            domfma(A1, B1);
            if (!have3) break;
            s1 = s3; mc1 = mc3;
        }
    }

    float* obase = out + (size_t)(b * T_DIM + t) * LD_ROW;
#pragma unroll
    for (int rg = 0; rg < NR; ++rg)
#pragma unroll
        for (int cg = 0; cg < 4; ++cg) {
            int d = cg * 16 + fr;
#pragma unroll
            for (int r = 0; r < 4; ++r) {
                int i = i0 + rg * 16 + kg * 4 + r;
                if (NR == 4 || i < L_DIM) obase[(size_t)i * D_DIM + d] = acc[rg][cg][r];
            }
        }
}

__global__ void __launch_bounds__(64) k_out(const unsigned short* __restrict__ pp,
                                            const unsigned short* __restrict__ xt,
                                            float* __restrict__ out) {
    // XCD swizzle: id&7 -> (b, t-quarter); each XCD reads one xt t-window.
    int id = blockIdx.x;
    int low = id & 7;
    int b = low >> 2, tq = low & 3;
    int rest = id >> 3;          // 0..319
    int tt = rest >> 2;          // 0..79
    int it = rest & 3;
    int t = tq * TSPLIT + tt;
    int i0 = it * 64;
    if (it < 3) out_body<4>(pp, xt, out, b, t, i0);
    else        out_body<1>(pp, xt, out, b, t, i0);
}

extern "C" void kernel_launch(void* const* d_in, const int* in_sizes, int n_in,
                              void* d_out, int out_size, void* d_ws, size_t ws_size,
                              hipStream_t stream) {
    const float* x = (const float*)d_in[0];
    const float* w = (const float*)d_in[1];
    float* out = (float*)d_out;

    char* ws = (char*)d_ws;
    size_t off = 0;
    auto carve = [&](size_t bytes) {
        void* p = ws + off;
        off += (bytes + 255) & ~(size_t)255;
        return p;
    };
    unsigned short* xbf = (unsigned short*)carve((size_t)B_DIM * T_DIM * LD_ROW * 2);          // 17.0 MB
    unsigned short* xt  = (unsigned short*)carve((size_t)B_DIM * T_DIM * D_DIM * MPAD * 2);    // 18.4 MB
    float* part         = (float*)carve((size_t)NSPLIT * B_DIM * J_TOT * L_DIM * 4);           // 28.8 MB
    float* psum         = (float*)carve((size_t)B_DIM * NCH_A * L_DIM * 4);                    // 53 KB
    unsigned short* pp  = (unsigned short*)carve((size_t)B_DIM * J_TOT * MPAD * 2);            // 3.9 MB

    k_prep<<<B_DIM * T_DIM, 256, 0, stream>>>(x, xbf, xt);
    k_sim<<<8 * 84, 256, 0, stream>>>(xbf, part);
    k_sumexp<<<dim3(NCH_A, B_DIM), 256, 0, stream>>>(part, w, psum);
    k_pack<<<dim3(NCH_P, B_DIM), 256, 0, stream>>>(part, w, psum, pp);
    k_out<<<B_DIM * T_DIM * 4, 64, 0, stream>>>(pp, xt, out);
}